// Round 8
// baseline (610.139 us; speedup 1.0000x reference)
//
#include <hip/hip_runtime.h>

// Graph2Col: stable stream compaction of (m=128, V=2048, R=32) int32 mapping.
// Valid (!= -1) entries first in row-major order; tail filled with -1.
// Output layout in d_out (int32): nodes_indices [total*2] then column_indices [total*3].
//
// R8: single-pass with TICKET-ORDERED decoupled lookback (CUB-style). Ticket
//     via device-scope atomicAdd makes work order == block start order, so
//     lookback is deadlock-free at ANY occupancy (no launch_bounds cap, no
//     dispatch-order assumption — R4's mistake fixed). Staging/writeout is
//     R7's proven structure: whole 2048-chunk staged as FINAL output dwords
//     in 40 KB LDS (4 blocks/CU), dense int4 copy-out, fused per-block tail
//     fill. d_ws (ticket + status) zeroed by in-graph hipMemsetAsync.

#define EMPTY_V (-1)

typedef int v4i __attribute__((ext_vector_type(4)));

constexpr int TOTAL = 8388608;                 // 128*2048*32
constexpr int BLOCK = 256;
constexpr int CHUNK = 2048;                    // elements per block
constexpr int NB = TOTAL / CHUNK;              // 4096 blocks
constexpr int SUBT = CHUNK / (BLOCK * 4);      // 2 sub-tiles of 1024 elements
constexpr int NWAVE = BLOCK / 64;              // 4 waves

// status word: top nibble 0=not ready (memset), 1=aggregate, 2=incl prefix.
// value in low 28 bits (max 8.4M < 2^28).

// dense dword copy LDS -> global with 16B-alignment peel, plain stores
__device__ __forceinline__ void copy_out(int* __restrict__ dst,
                                         const int* __restrict__ src,
                                         int ndw, int tid) {
    const int mis = (int)(((uintptr_t)dst >> 2) & 3);
    int peel = mis ? (4 - mis) : 0;
    if (peel > ndw) peel = ndw;
    if (tid < peel) dst[tid] = src[tid];
    const int body = (ndw - peel) >> 2;
    v4i* d4 = (v4i*)(dst + peel);
    const int* s4 = src + peel;
    for (int k = tid; k < body; k += BLOCK) {
        v4i t = {s4[4 * k], s4[4 * k + 1], s4[4 * k + 2], s4[4 * k + 3]};
        d4[k] = t;
    }
    const int tails = ndw - peel - 4 * body;
    if (tid < tails) {
        const int ld = peel + 4 * body + tid;
        dst[ld] = src[ld];
    }
}

__global__ __launch_bounds__(BLOCK) void k_fused(const int* __restrict__ in,
                                                 int* __restrict__ ticket,
                                                 unsigned* __restrict__ status,
                                                 int* __restrict__ out_nodes,
                                                 int* __restrict__ out_cols) {
    const int tid = threadIdx.x;
    const int lane = tid & 63, wid = tid >> 6;
    const unsigned long long below = lane ? ((~0ull) >> (64 - lane)) : 0ull;

    __shared__ int s_nodes[2 * CHUNK];   // 16 KB (head doubles as scratch)
    __shared__ int s_cols[3 * CHUNK];    // 24 KB
    int* WSUM = s_nodes + 0;             // [SUBT*NWAVE] per-subtile wave totals
    // s_nodes[12] = ticket, s_nodes[13] = excl (scratch, freed before staging)

    // ---- take a ticket: work id == block start order (deadlock-free lookback)
    if (tid == 0) s_nodes[12] = atomicAdd(ticket, 1);
    __syncthreads();                               // B1: ticket visible
    const int b = s_nodes[12];

    // ---- load chunk, ballots, publish per-wave totals
    int4 v[SUBT];
    int pre[SUBT];
    const int4* p = (const int4*)(in + (size_t)b * CHUNK);
#pragma unroll
    for (int s = 0; s < SUBT; ++s) {
        v[s] = p[s * BLOCK + tid];
        const unsigned long long b0 = __ballot(v[s].x != EMPTY_V);
        const unsigned long long b1 = __ballot(v[s].y != EMPTY_V);
        const unsigned long long b2 = __ballot(v[s].z != EMPTY_V);
        const unsigned long long b3 = __ballot(v[s].w != EMPTY_V);
        pre[s] = __popcll(b0 & below) + __popcll(b1 & below) +
                 __popcll(b2 & below) + __popcll(b3 & below);
        if (lane == 0)
            WSUM[s * NWAVE + wid] =
                __popcll(b0) + __popcll(b1) + __popcll(b2) + __popcll(b3);
    }
    __syncthreads();                               // B2: WSUM visible

    int myoff[SUBT];
    int acc = 0;
#pragma unroll
    for (int s = 0; s < SUBT; ++s) {
        int cs_ = 0, woff = 0;
#pragma unroll
        for (int w = 0; w < NWAVE; ++w) {
            const int x = WSUM[s * NWAVE + w];
            cs_ += x;
            if (w < wid) woff += x;
        }
        myoff[s] = acc + woff + pre[s];
        acc += cs_;
    }
    const int blockValid = acc;                    // block aggregate

    // ---- decoupled lookback (wave 0 only; others wait at B3)
    if (wid == 0) {
        if (b == 0) {
            if (lane == 0) {
                __hip_atomic_store(&status[0], 0x20000000u | (unsigned)blockValid,
                                   __ATOMIC_RELEASE, __HIP_MEMORY_SCOPE_AGENT);
                s_nodes[13] = 0;
            }
        } else {
            if (lane == 0)
                __hip_atomic_store(&status[b], 0x10000000u | (unsigned)blockValid,
                                   __ATOMIC_RELEASE, __HIP_MEMORY_SCOPE_AGENT);
            int excl = 0, idx = b;
            while (true) {
                const int pb = idx - 1 - lane;
                unsigned st;
                if (pb >= 0) {
                    do {
                        st = __hip_atomic_load(&status[pb], __ATOMIC_ACQUIRE,
                                               __HIP_MEMORY_SCOPE_AGENT);
                    } while ((st >> 28) == 0u);
                } else {
                    st = 0x20000000u;  // virtual block with prefix 0
                }
                const unsigned fl = st >> 28;
                int contrib = (int)(st & 0x0FFFFFFFu);
                const unsigned long long pm = __ballot(fl == 2u);
                if (pm) {
                    const int Lmin = __ffsll((unsigned long long)pm) - 1;
                    if (lane > Lmin) contrib = 0;   // aggs below + closest prefix
                    for (int d = 32; d; d >>= 1) contrib += __shfl_down(contrib, d, 64);
                    excl += contrib;
                    break;
                } else {
                    for (int d = 32; d; d >>= 1) contrib += __shfl_down(contrib, d, 64);
                    excl += contrib;
                    idx -= 64;
                }
            }
            if (lane == 0) {
                __hip_atomic_store(&status[b],
                                   0x20000000u | (unsigned)(excl + blockValid),
                                   __ATOMIC_RELEASE, __HIP_MEMORY_SCOPE_AGENT);
                s_nodes[13] = excl;
            }
        }
    }
    __syncthreads();                               // B3: excl visible
    const int excl = s_nodes[13];
    __syncthreads();                               // B4: scratch consumed

    // ---- stage final output dwords at compacted local ranks
    const int row = b >> 5;        // 2048 elems/block, 65536 elems/output-row
#pragma unroll
    for (int s = 0; s < SUBT; ++s) {
        int lp = myoff[s];
        const int rem0 = ((b & 31) << 11) + (s << 10) + (tid << 2);  // fi & 65535
        const int vals[4] = {v[s].x, v[s].y, v[s].z, v[s].w};
#pragma unroll
        for (int j = 0; j < 4; ++j) {
            if (vals[j] != EMPTY_V) {
                const int pp = rem0 + j;
                s_nodes[2 * lp] = row;
                s_nodes[2 * lp + 1] = vals[j];
                s_cols[3 * lp] = row;
                s_cols[3 * lp + 1] = pp >> 5;
                s_cols[3 * lp + 2] = pp & 31;
                ++lp;
            }
        }
    }
    __syncthreads();                               // B5: staging complete

    // ---- dense copy-out (pure streaming, no per-dword arithmetic)
    copy_out(out_nodes + 2 * (size_t)excl, s_nodes, 2 * blockValid, tid);
    copy_out(out_cols + 3 * (size_t)excl, s_cols, 3 * blockValid, tid);

    // ---- tail: this block's invalid entries, counted from the end.
    {
        const int inv_pref = b * CHUNK - excl;     // invalids before this block
        const int start = TOTAL - inv_pref - (CHUNK - blockValid);
        const int end = TOTAL - inv_pref;
        for (int pos = start + tid; pos < end; pos += BLOCK) {
            out_nodes[2 * pos]     = EMPTY_V;
            out_nodes[2 * pos + 1] = EMPTY_V;
            out_cols[3 * pos]      = EMPTY_V;
            out_cols[3 * pos + 1]  = EMPTY_V;
            out_cols[3 * pos + 2]  = EMPTY_V;
        }
    }
}

extern "C" void kernel_launch(void* const* d_in, const int* in_sizes, int n_in,
                              void* d_out, int out_size, void* d_ws, size_t ws_size,
                              hipStream_t stream) {
    const int* in = (const int*)d_in[0];
    int* out = (int*)d_out;
    int* out_nodes = out;                    // [TOTAL, 2] int32
    int* out_cols = out + 2 * (size_t)TOTAL; // [TOTAL, 3] int32
    int* ticket = (int*)d_ws;                // [1]
    unsigned* status = (unsigned*)d_ws + 1;  // [NB]

    // zero ticket + status (d_ws is poisoned 0xAA before every timed launch)
    hipMemsetAsync(d_ws, 0, (NB + 1) * sizeof(int), stream);
    k_fused<<<NB, BLOCK, 0, stream>>>(in, ticket, status, out_nodes, out_cols);
}

// Round 9
// 189.537 us; speedup vs baseline: 3.2191x; 3.2191x over previous
//
#include <hip/hip_runtime.h>

// Graph2Col: stable stream compaction of (m=128, V=2048, R=32) int32 mapping.
// Valid (!= -1) entries first in row-major order; tail filled with -1.
// Output layout in d_out (int32): nodes_indices [total*2] then column_indices [total*3].
//
// R9 = R7 (best: 189.2 us), pure revert from R8's lookback regression.
//     Two kernels, whole-chunk LDS staging of the FINAL output dwords
//     (s_nodes[2*CHUNK] + s_cols[3*CHUNK] = 40 KB -> 4 blocks/CU). Writeout is
//     a pure dense LDS->global copy (no per-dword div/swizzle/select). Plain
//     int4 stores. Block-local redundant scan of counts[]; tail fill fused.
//     Single-pass lookback variants are proven losers on 8-XCD MI355X
//     (R4: occupancy-capped latency-bound; R8: serial cross-XCD prefix chain).

#define EMPTY_V (-1)

typedef int v4i __attribute__((ext_vector_type(4)));

constexpr int TOTAL = 8388608;                 // 128*2048*32
constexpr int BLOCK = 256;
constexpr int CHUNK = 2048;                    // elements per block
constexpr int NB = TOTAL / CHUNK;              // 4096 blocks
constexpr int SUBT = CHUNK / (BLOCK * 4);      // 2 sub-tiles of 1024 elements
constexpr int NWAVE = BLOCK / 64;              // 4 waves

// ---------------------------------------------------------------- count pass
__global__ __launch_bounds__(BLOCK) void k_count(const int* __restrict__ in,
                                                 int* __restrict__ counts) {
    const int b = blockIdx.x;
    const int tid = threadIdx.x;
    const int4* p = (const int4*)(in + (size_t)b * CHUNK);
    int c = 0;
#pragma unroll
    for (int s = 0; s < SUBT; ++s) {
        int4 v = p[s * BLOCK + tid];
        c += (v.x != EMPTY_V) + (v.y != EMPTY_V) + (v.z != EMPTY_V) + (v.w != EMPTY_V);
    }
    for (int d = 32; d; d >>= 1) c += __shfl_down(c, d, 64);
    __shared__ int ws[NWAVE];
    const int lane = tid & 63, wid = tid >> 6;
    if (lane == 0) ws[wid] = c;
    __syncthreads();
    if (tid == 0) counts[b] = ws[0] + ws[1] + ws[2] + ws[3];
}

// dense dword copy LDS -> global with 16B-alignment peel, plain stores
__device__ __forceinline__ void copy_out(int* __restrict__ dst,
                                         const int* __restrict__ src,
                                         int ndw, int tid) {
    const int mis = (int)(((uintptr_t)dst >> 2) & 3);
    int peel = mis ? (4 - mis) : 0;
    if (peel > ndw) peel = ndw;
    if (tid < peel) dst[tid] = src[tid];
    const int body = (ndw - peel) >> 2;
    v4i* d4 = (v4i*)(dst + peel);
    const int* s4 = src + peel;
    for (int k = tid; k < body; k += BLOCK) {
        v4i t = {s4[4 * k], s4[4 * k + 1], s4[4 * k + 2], s4[4 * k + 3]};
        d4[k] = t;
    }
    const int tails = ndw - peel - 4 * body;
    if (tid < tails) {
        const int ld = peel + 4 * body + tid;
        dst[ld] = src[ld];
    }
}

// ---------------------- scatter: scan + stage final dwords + copyout + tail
__global__ __launch_bounds__(BLOCK) void k_scatter(const int* __restrict__ in,
                                                   const int* __restrict__ counts,
                                                   int* __restrict__ out_nodes,
                                                   int* __restrict__ out_cols) {
    const int b = blockIdx.x;
    const int tid = threadIdx.x;
    const int lane = tid & 63, wid = tid >> 6;
    const unsigned long long below = lane ? ((~0ull) >> (64 - lane)) : 0ull;

    __shared__ int s_nodes[2 * CHUNK];   // 16 KB  (head 48 B doubles as scratch)
    __shared__ int s_cols[3 * CHUNK];    // 24 KB
    int* RED = s_nodes;                  // [NWAVE]      scan partials
    int* WSUM = s_nodes + NWAVE;         // [SUBT*NWAVE] per-subtile wave totals

    // ---- per-wave partials of the redundant scan over counts[NB]
    {
        int pa = 0;
        const int idx0 = tid * 16;
#pragma unroll
        for (int q = 0; q < 4; ++q) {
            const int4 c4 = ((const int4*)counts)[4 * tid + q];
            const int cs[4] = {c4.x, c4.y, c4.z, c4.w};
#pragma unroll
            for (int j = 0; j < 4; ++j)
                if (idx0 + 4 * q + j < b) pa += cs[j];
        }
        for (int d = 32; d; d >>= 1) pa += __shfl_down(pa, d, 64);
        if (lane == 0) RED[wid] = pa;
    }

    // ---- load chunk, ballots, publish per-wave totals
    int4 v[SUBT];
    int pre[SUBT];
    const int4* p = (const int4*)(in + (size_t)b * CHUNK);
#pragma unroll
    for (int s = 0; s < SUBT; ++s) {
        v[s] = p[s * BLOCK + tid];
        const unsigned long long b0 = __ballot(v[s].x != EMPTY_V);
        const unsigned long long b1 = __ballot(v[s].y != EMPTY_V);
        const unsigned long long b2 = __ballot(v[s].z != EMPTY_V);
        const unsigned long long b3 = __ballot(v[s].w != EMPTY_V);
        pre[s] = __popcll(b0 & below) + __popcll(b1 & below) +
                 __popcll(b2 & below) + __popcll(b3 & below);
        if (lane == 0)
            WSUM[s * NWAVE + wid] =
                __popcll(b0) + __popcll(b1) + __popcll(b2) + __popcll(b3);
    }
    __syncthreads();   // barrier 1: RED/WSUM visible

    // ---- read scan results into registers (scratch freed after barrier 2)
    const int excl = RED[0] + RED[1] + RED[2] + RED[3];
    int myoff[SUBT];
    int acc = 0;
#pragma unroll
    for (int s = 0; s < SUBT; ++s) {
        int cs_ = 0, woff = 0;
#pragma unroll
        for (int w = 0; w < NWAVE; ++w) {
            const int x = WSUM[s * NWAVE + w];
            cs_ += x;
            if (w < wid) woff += x;
        }
        myoff[s] = acc + woff + pre[s];
        acc += cs_;
    }
    const int blockValid = acc;
    __syncthreads();   // barrier 2: scratch consumed, staging may overwrite

    // ---- stage final output dwords at compacted local ranks
    const int row = b >> 5;        // 2048 elems/block, 65536 elems/output-row
#pragma unroll
    for (int s = 0; s < SUBT; ++s) {
        int lp = myoff[s];
        const int rem0 = ((b & 31) << 11) + (s << 10) + (tid << 2);  // fi & 65535
        const int vals[4] = {v[s].x, v[s].y, v[s].z, v[s].w};
#pragma unroll
        for (int j = 0; j < 4; ++j) {
            if (vals[j] != EMPTY_V) {
                const int pp = rem0 + j;
                s_nodes[2 * lp] = row;
                s_nodes[2 * lp + 1] = vals[j];
                s_cols[3 * lp] = row;
                s_cols[3 * lp + 1] = pp >> 5;
                s_cols[3 * lp + 2] = pp & 31;
                ++lp;
            }
        }
    }
    __syncthreads();   // barrier 3: staging complete

    // ---- dense copy-out (pure streaming, no per-dword arithmetic)
    copy_out(out_nodes + 2 * (size_t)excl, s_nodes, 2 * blockValid, tid);
    copy_out(out_cols + 3 * (size_t)excl, s_cols, 3 * blockValid, tid);

    // ---- tail: this block's invalid entries, counted from the end.
    {
        const int inv_pref = b * CHUNK - excl;            // invalids before this block
        const int start = TOTAL - inv_pref - (CHUNK - blockValid);
        const int end = TOTAL - inv_pref;
        for (int pos = start + tid; pos < end; pos += BLOCK) {
            out_nodes[2 * pos]     = EMPTY_V;
            out_nodes[2 * pos + 1] = EMPTY_V;
            out_cols[3 * pos]      = EMPTY_V;
            out_cols[3 * pos + 1]  = EMPTY_V;
            out_cols[3 * pos + 2]  = EMPTY_V;
        }
    }
}

extern "C" void kernel_launch(void* const* d_in, const int* in_sizes, int n_in,
                              void* d_out, int out_size, void* d_ws, size_t ws_size,
                              hipStream_t stream) {
    const int* in = (const int*)d_in[0];
    int* out = (int*)d_out;
    int* out_nodes = out;                    // [TOTAL, 2] int32
    int* out_cols = out + 2 * (size_t)TOTAL; // [TOTAL, 3] int32
    int* counts = (int*)d_ws;                // [NB]

    k_count<<<NB, BLOCK, 0, stream>>>(in, counts);
    k_scatter<<<NB, BLOCK, 0, stream>>>(in, counts, out_nodes, out_cols);
}